// Round 4
// baseline (155.736 us; speedup 1.0000x reference)
//
#include <hip/hip_runtime.h>

#define NTH 256
#define U1H_STRIDE 43008  // per-signal float2s: 8*2048 + 8*1024 + 8*512 + 56*256

// Large LDS (block-wide 1024/2048 FFTs + per-wave 512): 37 KB -> 4 blocks/CU.
struct SMemL {
  float2 A[2048];
  float2 B[2048];
  float2 tw[512];
  float red[4];
  float binred[4][7];
};
// Small LDS (per-wave 256 FFTs only): 16.9 KB -> 8 blocks/CU (wave-cap).
struct SMemS {
  float2 A[1024];  // 4 waves x 256
  float2 B[1024];
  float2 tw[64];
};

// Bank swizzle (measured conflict-free across all stage patterns).
__device__ __forceinline__ int swz(int i) { return i ^ (((i >> 4) & 3) * 5); }

__device__ __forceinline__ float2 cmul(float2 a, float2 b) {
  return make_float2(a.x * b.x - a.y * b.y, a.x * b.y + a.y * b.x);
}

__device__ __forceinline__ float wsum(float v) {
#pragma unroll
  for (int off = 1; off < 64; off <<= 1) v += __shfl_xor(v, off, 64);
  return v;
}

// tw[u] = e^{-2*pi*i*u/M}, u in [0, M/4).
template <int M>
__device__ __forceinline__ void init_twM(float2* tw) {
  constexpr int NE = M / 4;
#pragma unroll
  for (int i = 0; i < (NE + NTH - 1) / NTH; ++i) {
    const int u = (int)threadIdx.x + NTH * i;
    if (NE < NTH && u >= NE) break;
    float s, c;
    sincosf(-(6.283185307179586f / (float)M) * (float)u, &s, &c);
    tw[u] = make_float2(c, s);
  }
}

template <bool INV>
__device__ __forceinline__ void bfly4(float2* cur, float2* oth, const float2* tw,
                                      int j, int logs, int NQ) {
  const int s = 1 << logs;
  const float2 a = cur[swz(j)];
  const float2 b = cur[swz(j + NQ)];
  const float2 c = cur[swz(j + 2 * NQ)];
  const float2 d = cur[swz(j + 3 * NQ)];
  float2 w1 = tw[j & ~(s - 1)];
  if (INV) w1.y = -w1.y;
  const float2 w2 = cmul(w1, w1);
  const float2 w3 = cmul(w2, w1);
  const float t0x = a.x + c.x, t0y = a.y + c.y;
  const float t1x = a.x - c.x, t1y = a.y - c.y;
  const float t2x = b.x + d.x, t2y = b.y + d.y;
  const float bdx = b.x - d.x, bdy = b.y - d.y;
  const float sgn = INV ? -1.0f : 1.0f;
  const float t3x = sgn * bdy, t3y = -sgn * bdx;  // -i*(b-d) fwd, +i inv
  const int wb = (j & (s - 1)) + ((j >> logs) << (logs + 2));
  oth[swz(wb)]         = make_float2(t0x + t2x, t0y + t2y);
  oth[swz(wb + s)]     = cmul(w1, make_float2(t1x + t3x, t1y + t3y));
  oth[swz(wb + 2 * s)] = cmul(w2, make_float2(t0x - t2x, t0y - t2y));
  oth[swz(wb + 3 * s)] = cmul(w3, make_float2(t1x - t3x, t1y - t3y));
}

// Block-wide FFT, M in {1024, 2048} (barriers between stages).
template <int M, bool INV>
__device__ __forceinline__ float2* bfft(float2* A, float2* B, const float2* tw) {
  constexpr int NQ = M / 4;
  float2* cur = A;
  float2* oth = B;
#pragma unroll
  for (int st = 0; st < 5; ++st) {  // 4^5 = 1024
    const int logs = 2 * st;
    __syncthreads();
#pragma unroll
    for (int i = 0; i < NQ / NTH; ++i)
      bfly4<INV>(cur, oth, tw, (int)threadIdx.x + NTH * i, logs, NQ);
    float2* t = cur; cur = oth; oth = t;
  }
  if (M == 2048) {
    __syncthreads();
#pragma unroll
    for (int i = 0; i < M / (2 * NTH); ++i) {
      const int j = (int)threadIdx.x + NTH * i;
      const float2 a = cur[swz(j)];
      const float2 b = cur[swz(j + M / 2)];
      oth[swz(j)]         = make_float2(a.x + b.x, a.y + b.y);
      oth[swz(j + M / 2)] = make_float2(a.x - b.x, a.y - b.y);
    }
    float2* t = cur; cur = oth; oth = t;
  }
  __syncthreads();
  return cur;
}

// Per-wave FFT, M in {256, 512} — BARRIER-FREE. Wave-private Aw/Bw slices;
// same-wave LDS ops execute in order (single instruction stream, in-order LDS
// pipe), so no __syncthreads needed. Caller must barrier once after tw init.
template <int M, bool INV>
__device__ __forceinline__ float2* wfft(float2* Aw, float2* Bw, const float2* tw, int l) {
  constexpr int NQ = M / 4;  // 64 or 128
  float2* cur = Aw;
  float2* oth = Bw;
#pragma unroll
  for (int st = 0; st < 4; ++st) {  // 4^4 = 256
    const int logs = 2 * st;
#pragma unroll
    for (int i = 0; i < NQ / 64; ++i) bfly4<INV>(cur, oth, tw, l + 64 * i, logs, NQ);
    float2* t = cur; cur = oth; oth = t;
  }
  if (M == 512) {
#pragma unroll
    for (int i = 0; i < M / 128; ++i) {
      const int j = l + 64 * i;
      const float2 a = cur[swz(j)];
      const float2 b = cur[swz(j + M / 2)];
      oth[swz(j)]         = make_float2(a.x + b.x, a.y + b.y);
      oth[swz(j + M / 2)] = make_float2(a.x - b.x, a.y - b.y);
    }
    float2* t = cur; cur = oth; oth = t;
  }
  return cur;
}

__device__ __forceinline__ int u1h_off(int j1) {
  const int o = j1 >> 3;
  if (o == 0) return j1 * 2048;
  if (o == 1) return 16384 + (j1 - 8) * 1024;
  if (o == 2) return 24576 + (j1 - 16) * 512;
  return 28672 + (j1 - 24) * 256;
}

#define PHI1 0.29504296f    // e^{-1.220703125}
#define PHI2 0.0075683594f  // e^{-4.8828125}
#define PHI3 1.6944313e-5f  // e^{-10.986328125}

// ---------------- Stage A ----------------
__global__ __launch_bounds__(NTH) void kA(const float* __restrict__ x,
                                          float2* __restrict__ xh) {
  __shared__ SMemL sm;
  init_twM<2048>(sm.tw);
  const int n = blockIdx.x, b = n / 6, c = n % 6;
  const float* xp = x + (size_t)b * (2048 * 6) + c;
#pragma unroll
  for (int i = 0; i < 8; ++i) {
    const int t = (int)threadIdx.x + NTH * i;
    sm.A[swz(t)] = make_float2(xp[t * 6], 0.0f);
  }
  float2* P = bfft<2048, false>(sm.A, sm.B, sm.tw);
#pragma unroll
  for (int i = 0; i < 8; ++i) {
    const int t = (int)threadIdx.x + NTH * i;
    xh[(size_t)n * 2048 + t] = P[swz(t)];
  }
}

// ---------------- Stage B bodies ----------------
template <int M1>
__device__ __forceinline__ void kB_block(SMemL& sm, const float2* __restrict__ src,
                                         float2* __restrict__ U1h, float* __restrict__ out,
                                         int n, int b, int c, int j1) {
  init_twM<M1>(sm.tw);
  constexpr int F = 2048 / M1;
  const float xi = 0.4f * exp2f(-0.125f * (float)j1);
  const float sig = 0.1f * xi;
  const float inv2s2 = 1.0f / (2.0f * sig * sig);
#pragma unroll
  for (int i = 0; i < M1 / NTH; ++i) {
    const int m = (int)threadIdx.x + NTH * i;
    float2 acc = make_float2(0.0f, 0.0f);
#pragma unroll
    for (int q = 0; q < F; ++q) {
      const int f = m + q * M1;
      const float fr = (float)(f < 1024 ? f : f - 2048) * (1.0f / 2048.0f);
      const float d = fr - xi;
      const float g = __expf(-d * d * inv2s2);
      const float2 v = src[f];
      acc.x += v.x * g; acc.y += v.y * g;
    }
    sm.A[swz(m)] = acc;
  }
  float2* P = bfft<M1, true>(sm.A, sm.B, sm.tw);
#pragma unroll
  for (int i = 0; i < M1 / NTH; ++i) {
    const int m = (int)threadIdx.x + NTH * i;
    const float2 v = P[swz(m)];
    sm.A[swz(m)] = make_float2(sqrtf(v.x * v.x + v.y * v.y) * (1.0f / 2048.0f), 0.0f);
  }
  float2* P2 = bfft<M1, false>(sm.A, sm.B, sm.tw);
  float2* dst = U1h + (size_t)n * U1H_STRIDE + u1h_off(j1);
#pragma unroll
  for (int i = 0; i < M1 / NTH; ++i) {
    const int m = (int)threadIdx.x + NTH * i;
    dst[m] = P2[swz(m)];
  }
  const float invM = 1.0f / (float)M1;
  const float c0 = P2[0].x * invM;
  const float2 U1 = P2[1], U2 = P2[2], U3 = P2[3];
  const float k1 = PHI1 * 2.0f * invM, k2 = PHI2 * 2.0f * invM, k3 = PHI3 * 2.0f * invM;
  float part = 0.0f;
#pragma unroll
  for (int i = 0; i < M1 / NTH; ++i) {
    const int t = (int)threadIdx.x + NTH * i;
    float sv, cv;
    __sincosf((6.283185307179586f / (float)M1) * (float)t, &sv, &cv);
    float acc = c0 + k1 * (U1.x * cv - U1.y * sv);
    const float c2 = cv * cv - sv * sv, s2 = 2.0f * sv * cv;
    acc += k2 * (U2.x * c2 - U2.y * s2);
    const float c3 = c2 * cv - s2 * sv, s3 = s2 * cv + c2 * sv;
    acc += k3 * (U3.x * c3 - U3.y * s3);
    part += __logf(acc + 1e-6f);
  }
  part = wsum(part);
  const int lane = (int)threadIdx.x & 63, wid = (int)threadIdx.x >> 6;
  if (lane == 0) sm.red[wid] = part;
  __syncthreads();
  if (threadIdx.x == 0)
    out[((size_t)b * 440 + j1) * 6 + c] =
        (sm.red[0] + sm.red[1] + sm.red[2] + sm.red[3]) * invM;
}

template <int M1>
__device__ __forceinline__ void kB_wave(float2* A, float2* B, float2* tw,
                                        const float2* __restrict__ src,
                                        float2* __restrict__ U1h, float* __restrict__ out,
                                        int n, int b, int c, int j1base) {
  init_twM<M1>(tw);
  __syncthreads();  // tw visible to all waves; everything below is barrier-free
  const int l = (int)threadIdx.x & 63, wid = (int)threadIdx.x >> 6;
  const int j1 = j1base + wid;
  float2* Aw = A + wid * M1;
  float2* Bw = B + wid * M1;
  constexpr int F = 2048 / M1;
  const float xi = 0.4f * exp2f(-0.125f * (float)j1);
  const float sig = 0.1f * xi;
  const float inv2s2 = 1.0f / (2.0f * sig * sig);
#pragma unroll
  for (int i = 0; i < M1 / 64; ++i) {
    const int m = l + 64 * i;
    float2 acc = make_float2(0.0f, 0.0f);
#pragma unroll
    for (int q = 0; q < F; ++q) {
      const int f = m + q * M1;
      const float fr = (float)(f < 1024 ? f : f - 2048) * (1.0f / 2048.0f);
      const float d = fr - xi;
      const float g = __expf(-d * d * inv2s2);
      const float2 v = src[f];
      acc.x += v.x * g; acc.y += v.y * g;
    }
    Aw[swz(m)] = acc;
  }
  float2* P = wfft<M1, true>(Aw, Bw, tw, l);
#pragma unroll
  for (int i = 0; i < M1 / 64; ++i) {
    const int m = l + 64 * i;
    const float2 v = P[swz(m)];
    Aw[swz(m)] = make_float2(sqrtf(v.x * v.x + v.y * v.y) * (1.0f / 2048.0f), 0.0f);
  }
  float2* P2 = wfft<M1, false>(Aw, Bw, tw, l);
  float2* dst = U1h + (size_t)n * U1H_STRIDE + u1h_off(j1);
#pragma unroll
  for (int i = 0; i < M1 / 64; ++i) {
    const int m = l + 64 * i;
    dst[m] = P2[swz(m)];
  }
  const float invM = 1.0f / (float)M1;
  const float c0 = P2[0].x * invM;
  const float2 U1 = P2[1], U2 = P2[2], U3 = P2[3];
  const float k1 = PHI1 * 2.0f * invM, k2 = PHI2 * 2.0f * invM, k3 = PHI3 * 2.0f * invM;
  float part = 0.0f;
#pragma unroll
  for (int i = 0; i < M1 / 64; ++i) {
    const int t = l + 64 * i;
    float sv, cv;
    __sincosf((6.283185307179586f / (float)M1) * (float)t, &sv, &cv);
    float acc = c0 + k1 * (U1.x * cv - U1.y * sv);
    const float c2 = cv * cv - sv * sv, s2 = 2.0f * sv * cv;
    acc += k2 * (U2.x * c2 - U2.y * s2);
    const float c3 = c2 * cv - s2 * sv, s3 = s2 * cv + c2 * sv;
    acc += k3 * (U3.x * c3 - U3.y * s3);
    part += __logf(acc + 1e-6f);
  }
  part = wsum(part);
  if (l == 0) out[((size_t)b * 440 + j1) * 6 + c] = part * invM;
}

// kB_big: 18 blocks/signal: [0,8) M=2048; [8,16) M=1024; [16,18) M=512 per-wave.
__global__ __launch_bounds__(NTH, 4) void kB_big(const float2* __restrict__ xh,
                                                 float2* __restrict__ U1h,
                                                 float* __restrict__ out) {
  __shared__ SMemL sm;
  const int n = (int)blockIdx.x / 18;
  const int lc = (int)blockIdx.x % 18;
  const int b = n / 6, c = n % 6;
  const float2* src = xh + (size_t)n * 2048;
  if (lc < 8)       kB_block<2048>(sm, src, U1h, out, n, b, c, lc);
  else if (lc < 16) kB_block<1024>(sm, src, U1h, out, n, b, c, lc);
  else kB_wave<512>(sm.A, sm.B, sm.tw, src, U1h, out, n, b, c, 16 + 4 * (lc - 16));
}

// kB_s256: 14 blocks/signal, j1 in [24,80), 4 per block. Small LDS, 8 blocks/CU.
__global__ __launch_bounds__(NTH, 8) void kB_s256(const float2* __restrict__ xh,
                                                  float2* __restrict__ U1h,
                                                  float* __restrict__ out) {
  __shared__ SMemS sm;
  const int n = (int)blockIdx.x / 14;
  const int lc = (int)blockIdx.x % 14;
  const int b = n / 6, c = n % 6;
  const float2* src = xh + (size_t)n * 2048;
  kB_wave<256>(sm.A, sm.B, sm.tw, src, U1h, out, n, b, c, 24 + 4 * lc);
}

// ---------------- Stage C bodies ----------------
template <int M2>
__device__ __forceinline__ void kC_block(SMemL& sm, const float2* __restrict__ V,
                                         float* __restrict__ outp, int M1, int F, float xi) {
  init_twM<M2>(sm.tw);
  const float sig = 0.8f * xi;
  const float inv2s2 = 1.0f / (2.0f * sig * sig);
#pragma unroll
  for (int i = 0; i < M2 / NTH; ++i) {
    const int m = (int)threadIdx.x + NTH * i;
    float2 acc = make_float2(0.0f, 0.0f);
    for (int q = 0; q < F; ++q) {
      const int idx = m + q * M2;
      const float fr = (float)(idx < (M1 >> 1) ? idx : idx - M1) * (1.0f / 2048.0f);
      const float d = fr - xi;
      const float g = __expf(-d * d * inv2s2);
      const float2 v = V[idx];
      acc.x += v.x * g; acc.y += v.y * g;
    }
    sm.A[swz(m)] = acc;
  }
  float2* P = bfft<M2, true>(sm.A, sm.B, sm.tw);
  const float invM1 = 1.0f / (float)M1;
  float cvs[M2 / NTH], svs[M2 / NTH];
  float b0 = 0, b1r = 0, b1i = 0, b2r = 0, b2i = 0, b3r = 0, b3i = 0;
#pragma unroll
  for (int i = 0; i < M2 / NTH; ++i) {
    const int t = (int)threadIdx.x + NTH * i;
    const float2 v = P[swz(t)];
    const float u = sqrtf(v.x * v.x + v.y * v.y) * invM1;
    float sv, cv;
    __sincosf((6.283185307179586f / (float)M2) * (float)t, &sv, &cv);
    cvs[i] = cv; svs[i] = sv;
    b0 += u;
    b1r += u * cv; b1i -= u * sv;
    const float c2 = cv * cv - sv * sv, s2 = 2.0f * sv * cv;
    b2r += u * c2; b2i -= u * s2;
    const float c3 = c2 * cv - s2 * sv, s3 = s2 * cv + c2 * sv;
    b3r += u * c3; b3i -= u * s3;
  }
  b0 = wsum(b0);
  b1r = wsum(b1r); b1i = wsum(b1i);
  b2r = wsum(b2r); b2i = wsum(b2i);
  b3r = wsum(b3r); b3i = wsum(b3i);
  const int lane = (int)threadIdx.x & 63, wid = (int)threadIdx.x >> 6;
  if (lane == 0) {
    sm.binred[wid][0] = b0;
    sm.binred[wid][1] = b1r; sm.binred[wid][2] = b1i;
    sm.binred[wid][3] = b2r; sm.binred[wid][4] = b2i;
    sm.binred[wid][5] = b3r; sm.binred[wid][6] = b3i;
  }
  __syncthreads();
  float Bv[7];
#pragma unroll
  for (int bi = 0; bi < 7; ++bi)
    Bv[bi] = sm.binred[0][bi] + sm.binred[1][bi] + sm.binred[2][bi] + sm.binred[3][bi];
  const float k1 = 2.0f * PHI1, k2 = 2.0f * PHI2, k3 = 2.0f * PHI3;
  const float invM2 = 1.0f / (float)M2;
  float part = 0.0f;
#pragma unroll
  for (int i = 0; i < M2 / NTH; ++i) {
    const float cv = cvs[i], sv = svs[i];
    float acc = Bv[0] + k1 * (Bv[1] * cv - Bv[2] * sv);
    const float c2 = cv * cv - sv * sv, s2 = 2.0f * sv * cv;
    acc += k2 * (Bv[3] * c2 - Bv[4] * s2);
    const float c3 = c2 * cv - s2 * sv, s3 = s2 * cv + c2 * sv;
    acc += k3 * (Bv[5] * c3 - Bv[6] * s3);
    part += __logf(acc * invM2 + 1e-6f);
  }
  part = wsum(part);
  if (lane == 0) sm.red[wid] = part;
  __syncthreads();
  if (threadIdx.x == 0)
    *outp = (sm.red[0] + sm.red[1] + sm.red[2] + sm.red[3]) * invM2;
}

template <int M2>
__device__ __forceinline__ void kC_wave(float2* A, float2* B, float2* tw,
                                        const float2* __restrict__ V,
                                        float* __restrict__ outp, int M1, int F, float xi) {
  init_twM<M2>(tw);
  __syncthreads();  // tw visible; rest barrier-free
  const int l = (int)threadIdx.x & 63, wid = (int)threadIdx.x >> 6;
  float2* Aw = A + wid * M2;
  float2* Bw = B + wid * M2;
  const float sig = 0.8f * xi;
  const float inv2s2 = 1.0f / (2.0f * sig * sig);
#pragma unroll
  for (int i = 0; i < M2 / 64; ++i) {
    const int m = l + 64 * i;
    float2 acc = make_float2(0.0f, 0.0f);
    for (int q = 0; q < F; ++q) {
      const int idx = m + q * M2;
      const float fr = (float)(idx < (M1 >> 1) ? idx : idx - M1) * (1.0f / 2048.0f);
      const float d = fr - xi;
      const float g = __expf(-d * d * inv2s2);
      const float2 v = V[idx];
      acc.x += v.x * g; acc.y += v.y * g;
    }
    Aw[swz(m)] = acc;
  }
  float2* P = wfft<M2, true>(Aw, Bw, tw, l);
  const float invM1 = 1.0f / (float)M1;
  float cvs[M2 / 64], svs[M2 / 64];
  float b0 = 0, b1r = 0, b1i = 0, b2r = 0, b2i = 0, b3r = 0, b3i = 0;
#pragma unroll
  for (int i = 0; i < M2 / 64; ++i) {
    const int t = l + 64 * i;
    const float2 v = P[swz(t)];
    const float u = sqrtf(v.x * v.x + v.y * v.y) * invM1;
    float sv, cv;
    __sincosf((6.283185307179586f / (float)M2) * (float)t, &sv, &cv);
    cvs[i] = cv; svs[i] = sv;
    b0 += u;
    b1r += u * cv; b1i -= u * sv;
    const float c2 = cv * cv - sv * sv, s2 = 2.0f * sv * cv;
    b2r += u * c2; b2i -= u * s2;
    const float c3 = c2 * cv - s2 * sv, s3 = s2 * cv + c2 * sv;
    b3r += u * c3; b3i -= u * s3;
  }
  b0 = wsum(b0);
  b1r = wsum(b1r); b1i = wsum(b1i);
  b2r = wsum(b2r); b2i = wsum(b2i);
  b3r = wsum(b3r); b3i = wsum(b3i);
  const float k1 = 2.0f * PHI1, k2 = 2.0f * PHI2, k3 = 2.0f * PHI3;
  const float invM2 = 1.0f / (float)M2;
  float part = 0.0f;
#pragma unroll
  for (int i = 0; i < M2 / 64; ++i) {
    const float cv = cvs[i], sv = svs[i];
    float acc = b0 + k1 * (b1r * cv - b1i * sv);
    const float c2 = cv * cv - sv * sv, s2 = 2.0f * sv * cv;
    acc += k2 * (b2r * c2 - b2i * s2);
    const float c3 = c2 * cv - s2 * sv, s3 = s2 * cv + c2 * sv;
    acc += k3 * (b3r * c3 - b3i * s3);
    part += __logf(acc * invM2 + 1e-6f);
  }
  part = wsum(part);
  if (l == 0) *outp = part * invM2;
}

// kC_big: 30 blocks/signal: [0,8) k=1 M2=2048; [8,24) k=2 M2=1024; [24,30) k=3
// M2=512 per-wave.
__global__ __launch_bounds__(NTH, 4) void kC_big(const float2* __restrict__ U1h,
                                                 float* __restrict__ out) {
  __shared__ SMemL sm;
  const int n = (int)blockIdx.x / 30;
  const int lc = (int)blockIdx.x % 30;
  const int b = n / 6, c = n % 6;
  const float2* base = U1h + (size_t)n * U1H_STRIDE;
  const int wid = (int)threadIdx.x >> 6;
  if (lc < 8) {
    const int j1 = lc, k = 1;
    const float xi = 0.4f * exp2f(-(float)k);
    const int p = 4 * k * (k - 1) + j1;
    kC_block<2048>(sm, base + u1h_off(j1), out + ((size_t)b * 440 + 80 + p) * 6 + c,
                   2048, 1, xi);
  } else if (lc < 24) {
    const int j1 = lc - 8, k = 2;
    const int o = j1 >> 3;
    const int M1 = 2048 >> o;
    const float xi = 0.4f * exp2f(-(float)k);
    const int p = 4 * k * (k - 1) + j1;
    kC_block<1024>(sm, base + u1h_off(j1), out + ((size_t)b * 440 + 80 + p) * 6 + c,
                   M1, M1 / 1024, xi);
  } else {
    const int g = lc - 24, k = 3;
    const int j1 = 4 * g + wid;
    const int o = j1 >> 3;
    const int M1 = 2048 >> o;
    const float xi = 0.4f * exp2f(-(float)k);
    const int p = 4 * k * (k - 1) + j1;
    kC_wave<512>(sm.A, sm.B, sm.tw, base + u1h_off(j1),
                 out + ((size_t)b * 440 + 80 + p) * 6 + c, M1, M1 / 512, xi);
  }
}

// kC_s256: 78 blocks/signal: k in 4..9, 2k groups each, 4 paths/block.
__global__ __launch_bounds__(NTH, 8) void kC_s256(const float2* __restrict__ U1h,
                                                  float* __restrict__ out) {
  __shared__ SMemS sm;
  const int n = (int)blockIdx.x / 78;
  int bc = (int)blockIdx.x % 78;
  const int b = n / 6, c = n % 6;
  const float2* base = U1h + (size_t)n * U1H_STRIDE;
  const int wid = (int)threadIdx.x >> 6;
  int k = 4;
  while (bc >= 2 * k) { bc -= 2 * k; ++k; }
  const int j1 = 4 * bc + wid;
  const int o = j1 >> 3;
  const int M1 = (o < 3) ? (2048 >> o) : 256;
  const float xi = 0.4f * exp2f(-(float)k);
  const int p = 4 * k * (k - 1) + j1;
  kC_wave<256>(sm.A, sm.B, sm.tw, base + u1h_off(j1),
               out + ((size_t)b * 440 + 80 + p) * 6 + c, M1, M1 / 256, xi);
}

extern "C" void kernel_launch(void* const* d_in, const int* in_sizes, int n_in,
                              void* d_out, int out_size, void* d_ws, size_t ws_size,
                              hipStream_t stream) {
  (void)in_sizes; (void)n_in; (void)out_size; (void)ws_size;
  const float* x = (const float*)d_in[0];  // [8, 2048, 6] fp32
  float* out = (float*)d_out;              // [8, 440, 6] fp32
  float2* U1h = (float2*)d_ws;                                       // 16.5 MB
  float2* xh = (float2*)((char*)d_ws + (size_t)48 * U1H_STRIDE * sizeof(float2));
  kA<<<dim3(48), dim3(NTH), 0, stream>>>(x, xh);
  kB_big<<<dim3(48 * 18), dim3(NTH), 0, stream>>>(xh, U1h, out);
  kB_s256<<<dim3(48 * 14), dim3(NTH), 0, stream>>>(xh, U1h, out);
  kC_big<<<dim3(48 * 30), dim3(NTH), 0, stream>>>(U1h, out);
  kC_s256<<<dim3(48 * 78), dim3(NTH), 0, stream>>>(U1h, out);
}

// Round 5
// 126.153 us; speedup vs baseline: 1.2345x; 1.2345x over previous
//
#include <hip/hip_runtime.h>

#define NTH 256
#define U1H_STRIDE 43008  // per-signal float2s: 8*2048 + 8*1024 + 8*512 + 56*256

// Exactly 20480 B -> 8 blocks/CU (was 37 KB / 4 blocks). Reduction scratch is
// overlaid on tw (tw is dead once the last FFT stage has run).
struct SM {
  float2 A[2048];
  float2 tw[512];
};

// Bank swizzle — verified conflict-free for in-place strides {1,2,4,...,512}.
__device__ __forceinline__ int swz(int i) { return i ^ (((i >> 4) & 3) * 5); }

__device__ __forceinline__ float2 cmul(float2 a, float2 b) {
  return make_float2(a.x * b.x - a.y * b.y, a.x * b.y + a.y * b.x);
}

__device__ __forceinline__ float wsum(float v) {
#pragma unroll
  for (int off = 1; off < 64; off <<= 1) v += __shfl_xor(v, off, 64);
  return v;
}

template <int M>
__device__ __forceinline__ void init_twM(float2* tw) {
  constexpr int NE = M / 4;
#pragma unroll
  for (int i = 0; i < (NE + NTH - 1) / NTH; ++i) {
    const int u = (int)threadIdx.x + NTH * i;
    if (NE < NTH && u >= NE) break;
    float s, c;
    sincosf(-(6.283185307179586f / (float)M) * (float)u, &s, &c);
    tw[u] = make_float2(c, s);
  }
}

// P(idx): output-frequency of storage slot idx after the DIF stage sequence.
// (mixed-radix digit transposition; verified by hand at M=4, M=8.)
template <int M>
__device__ __forceinline__ int prevM(int i) {
  if (M == 256)
    return ((i & 3) << 6) | (((i >> 2) & 3) << 4) | (((i >> 4) & 3) << 2) | ((i >> 6) & 3);
  else if (M == 512)
    return ((i >> 7) & 3) | (((i >> 5) & 3) << 2) | (((i >> 3) & 3) << 4) |
           (((i >> 1) & 3) << 6) | ((i & 1) << 8);
  else if (M == 1024)
    return ((i >> 8) & 3) | (((i >> 6) & 3) << 2) | (((i >> 4) & 3) << 4) |
           (((i >> 2) & 3) << 6) | ((i & 3) << 8);
  else
    return ((i >> 9) & 3) | (((i >> 7) & 3) << 2) | (((i >> 5) & 3) << 4) |
           (((i >> 3) & 3) << 6) | (((i >> 1) & 3) << 8) | ((i & 1) << 10);
}

// In-place radix-4 DIF stage (butterfly, then twiddle). INV: conj network.
template <bool INV, int LM>
__device__ __forceinline__ void dif4(float2* A, const float2* tw, int j, int ls) {
  const int s = 1 << ls;
  const int e = j & (s - 1);
  const int base = ((j >> ls) << (ls + 2)) | e;
  const float2 a0 = A[swz(base)];
  const float2 a1 = A[swz(base + s)];
  const float2 a2 = A[swz(base + 2 * s)];
  const float2 a3 = A[swz(base + 3 * s)];
  float2 w1 = tw[e << (LM - ls - 2)];
  if (INV) w1.y = -w1.y;
  const float2 w2 = cmul(w1, w1);
  const float2 w3 = cmul(w2, w1);
  const float t0x = a0.x + a2.x, t0y = a0.y + a2.y;
  const float t1x = a0.x - a2.x, t1y = a0.y - a2.y;
  const float t2x = a1.x + a3.x, t2y = a1.y + a3.y;
  const float bdx = a1.x - a3.x, bdy = a1.y - a3.y;
  const float sgn = INV ? -1.0f : 1.0f;
  const float t3x = sgn * bdy, t3y = -sgn * bdx;  // fwd: -i*(a1-a3); inv: +i
  A[swz(base)]         = make_float2(t0x + t2x, t0y + t2y);
  A[swz(base + s)]     = cmul(make_float2(t1x + t3x, t1y + t3y), w1);
  A[swz(base + 2 * s)] = cmul(make_float2(t0x - t2x, t0y - t2y), w2);
  A[swz(base + 3 * s)] = cmul(make_float2(t1x - t3x, t1y - t3y), w3);
}

// In-place radix-4 DIT stage (twiddle-before; transpose of dif4). Forward only.
template <int LM>
__device__ __forceinline__ void dit4(float2* A, const float2* tw, int j, int ls) {
  const int s = 1 << ls;
  const int e = j & (s - 1);
  const int base = ((j >> ls) << (ls + 2)) | e;
  const float2 w1 = tw[e << (LM - ls - 2)];
  const float2 w2 = cmul(w1, w1);
  const float2 w3 = cmul(w2, w1);
  const float2 c0 = A[swz(base)];
  const float2 c1 = cmul(A[swz(base + s)], w1);
  const float2 c2 = cmul(A[swz(base + 2 * s)], w2);
  const float2 c3 = cmul(A[swz(base + 3 * s)], w3);
  const float t0x = c0.x + c2.x, t0y = c0.y + c2.y;
  const float t1x = c0.x - c2.x, t1y = c0.y - c2.y;
  const float t2x = c1.x + c3.x, t2y = c1.y + c3.y;
  const float bdx = c1.x - c3.x, bdy = c1.y - c3.y;
  const float t3x = bdy, t3y = -bdx;  // -i*(c1-c3)
  A[swz(base)]         = make_float2(t0x + t2x, t0y + t2y);
  A[swz(base + s)]     = make_float2(t1x + t3x, t1y + t3y);
  A[swz(base + 2 * s)] = make_float2(t0x - t2x, t0y - t2y);
  A[swz(base + 3 * s)] = make_float2(t1x - t3x, t1y - t3y);
}

__device__ __forceinline__ void r2pair(float2* A, int g) {
  const float2 a = A[swz(2 * g)];
  const float2 b = A[swz(2 * g + 1)];
  A[swz(2 * g)]     = make_float2(a.x + b.x, a.y + b.y);
  A[swz(2 * g + 1)] = make_float2(a.x - b.x, a.y - b.y);
}

// Block-wide in-place DIF: natural -> P-order. M in {1024, 2048}.
template <int M, bool INV>
__device__ __forceinline__ void dif_blk(float2* A, const float2* tw) {
  constexpr int LM = (M == 2048) ? 11 : 10;
  constexpr int NB = M / 4;
#pragma unroll
  for (int ls = LM - 2; ls >= (LM & 1); ls -= 2) {
    __syncthreads();
#pragma unroll
    for (int i = 0; i < NB / NTH; ++i)
      dif4<INV, LM>(A, tw, (int)threadIdx.x + NTH * i, ls);
  }
  if (LM & 1) {
    __syncthreads();
#pragma unroll
    for (int i = 0; i < (M / 2) / NTH; ++i) r2pair(A, (int)threadIdx.x + NTH * i);
  }
  __syncthreads();
}

// Block-wide in-place DIT (forward): P-order -> natural.
template <int M>
__device__ __forceinline__ void dit_blk(float2* A, const float2* tw) {
  constexpr int LM = (M == 2048) ? 11 : 10;
  constexpr int NB = M / 4;
  if (LM & 1) {
    __syncthreads();
#pragma unroll
    for (int i = 0; i < (M / 2) / NTH; ++i) r2pair(A, (int)threadIdx.x + NTH * i);
  }
#pragma unroll
  for (int ls = (LM & 1); ls <= LM - 2; ls += 2) {
    __syncthreads();
#pragma unroll
    for (int i = 0; i < NB / NTH; ++i)
      dit4<LM>(A, tw, (int)threadIdx.x + NTH * i, ls);
  }
  __syncthreads();
}

// Per-wave, barrier-free (wave-private Aw slice). M in {256, 512}.
template <int M, bool INV>
__device__ __forceinline__ void dif_wav(float2* Aw, const float2* tw, int l) {
  constexpr int LM = (M == 512) ? 9 : 8;
  constexpr int NB = M / 4;
#pragma unroll
  for (int ls = LM - 2; ls >= (LM & 1); ls -= 2) {
#pragma unroll
    for (int i = 0; i < NB / 64; ++i) dif4<INV, LM>(Aw, tw, l + 64 * i, ls);
  }
  if (LM & 1) {
#pragma unroll
    for (int i = 0; i < (M / 2) / 64; ++i) r2pair(Aw, l + 64 * i);
  }
}

template <int M>
__device__ __forceinline__ void dit_wav(float2* Aw, const float2* tw, int l) {
  constexpr int LM = (M == 512) ? 9 : 8;
  constexpr int NB = M / 4;
  if (LM & 1) {
#pragma unroll
    for (int i = 0; i < (M / 2) / 64; ++i) r2pair(Aw, l + 64 * i);
  }
#pragma unroll
  for (int ls = (LM & 1); ls <= LM - 2; ls += 2) {
#pragma unroll
    for (int i = 0; i < NB / 64; ++i) dit4<LM>(Aw, tw, l + 64 * i, ls);
  }
}

__device__ __forceinline__ int u1h_off(int j1) {
  const int o = j1 >> 3;
  if (o == 0) return j1 * 2048;
  if (o == 1) return 16384 + (j1 - 8) * 1024;
  if (o == 2) return 24576 + (j1 - 16) * 512;
  return 28672 + (j1 - 24) * 256;
}

#define PHI1 0.29504296f    // e^{-1.220703125}
#define PHI2 0.0075683594f  // e^{-4.8828125}
#define PHI3 1.6944313e-5f  // e^{-10.986328125}

// ---------------- Stage A: xh = fft(x), natural order via P-scatter ----------
__global__ __launch_bounds__(NTH) void kA(const float* __restrict__ x,
                                          float2* __restrict__ xh) {
  __shared__ SM sm;
  init_twM<2048>(sm.tw);
  const int n = blockIdx.x, b = n / 6, c = n % 6;
  const float* xp = x + (size_t)b * (2048 * 6) + c;
#pragma unroll
  for (int i = 0; i < 8; ++i) {
    const int t = (int)threadIdx.x + NTH * i;
    sm.A[swz(t)] = make_float2(xp[t * 6], 0.0f);
  }
  dif_blk<2048, false>(sm.A, sm.tw);
#pragma unroll
  for (int i = 0; i < 8; ++i) {
    const int t = (int)threadIdx.x + NTH * i;
    xh[(size_t)n * 2048 + prevM<2048>(t)] = sm.A[swz(t)];
  }
}

// ---------------- Stage B bodies ----------------
template <int M1>
__device__ __forceinline__ void kB_blk(SM& sm, const float2* __restrict__ src,
                                       float2* __restrict__ U1h, float* __restrict__ out,
                                       int n, int b, int c, int j1) {
  init_twM<M1>(sm.tw);
  constexpr int F = 2048 / M1;
  const float xi = 0.4f * exp2f(-0.125f * (float)j1);
  const float sig = 0.1f * xi;
  const float inv2s2 = 1.0f / (2.0f * sig * sig);
#pragma unroll
  for (int i = 0; i < M1 / NTH; ++i) {
    const int m = (int)threadIdx.x + NTH * i;
    float2 acc = make_float2(0.0f, 0.0f);
#pragma unroll
    for (int q = 0; q < F; ++q) {
      const int f = m + q * M1;
      const float fr = (float)(f < 1024 ? f : f - 2048) * (1.0f / 2048.0f);
      const float d = fr - xi;
      const float g = __expf(-d * d * inv2s2);
      const float2 v = src[f];
      acc.x += v.x * g; acc.y += v.y * g;
    }
    sm.A[swz(m)] = acc;
  }
  dif_blk<M1, true>(sm.A, sm.tw);  // z in P-order (unnormalized inverse)
#pragma unroll
  for (int i = 0; i < M1 / NTH; ++i) {
    const int m = (int)threadIdx.x + NTH * i;
    const float2 v = sm.A[swz(m)];
    sm.A[swz(m)] = make_float2(sqrtf(v.x * v.x + v.y * v.y) * (1.0f / 2048.0f), 0.0f);
  }
  dit_blk<M1>(sm.A, sm.tw);        // V natural (digit-reversal cancels)
  float2* dst = U1h + (size_t)n * U1H_STRIDE + u1h_off(j1);
#pragma unroll
  for (int i = 0; i < M1 / NTH; ++i) {
    const int m = (int)threadIdx.x + NTH * i;
    dst[m] = sm.A[swz(m)];
  }
  const float invM = 1.0f / (float)M1;
  const float c0 = sm.A[0].x * invM;  // swz identity for idx<16
  const float2 U1 = sm.A[1], U2 = sm.A[2], U3 = sm.A[3];
  const float k1 = PHI1 * 2.0f * invM, k2 = PHI2 * 2.0f * invM, k3 = PHI3 * 2.0f * invM;
  float part = 0.0f;
#pragma unroll
  for (int i = 0; i < M1 / NTH; ++i) {
    const int t = (int)threadIdx.x + NTH * i;
    float sv, cv;
    __sincosf((6.283185307179586f / (float)M1) * (float)t, &sv, &cv);
    float acc = c0 + k1 * (U1.x * cv - U1.y * sv);
    const float c2 = cv * cv - sv * sv, s2 = 2.0f * sv * cv;
    acc += k2 * (U2.x * c2 - U2.y * s2);
    const float c3 = c2 * cv - s2 * sv, s3 = s2 * cv + c2 * sv;
    acc += k3 * (U3.x * c3 - U3.y * s3);
    part += __logf(acc + 1e-6f);
  }
  part = wsum(part);
  float* red = (float*)sm.tw;  // tw dead after dit
  const int lane = (int)threadIdx.x & 63, wid = (int)threadIdx.x >> 6;
  if (lane == 0) red[wid] = part;
  __syncthreads();
  if (threadIdx.x == 0)
    out[((size_t)b * 440 + j1) * 6 + c] = (red[0] + red[1] + red[2] + red[3]) * invM;
}

template <int M1>
__device__ __forceinline__ void kB_wav(SM& sm, const float2* __restrict__ src,
                                       float2* __restrict__ U1h, float* __restrict__ out,
                                       int n, int b, int c, int j1base) {
  init_twM<M1>(sm.tw);
  __syncthreads();  // tw visible; everything below barrier-free
  const int l = (int)threadIdx.x & 63, wid = (int)threadIdx.x >> 6;
  const int j1 = j1base + wid;
  float2* Aw = sm.A + wid * M1;
  constexpr int F = 2048 / M1;
  const float xi = 0.4f * exp2f(-0.125f * (float)j1);
  const float sig = 0.1f * xi;
  const float inv2s2 = 1.0f / (2.0f * sig * sig);
#pragma unroll
  for (int i = 0; i < M1 / 64; ++i) {
    const int m = l + 64 * i;
    float2 acc = make_float2(0.0f, 0.0f);
#pragma unroll
    for (int q = 0; q < F; ++q) {
      const int f = m + q * M1;
      const float fr = (float)(f < 1024 ? f : f - 2048) * (1.0f / 2048.0f);
      const float d = fr - xi;
      const float g = __expf(-d * d * inv2s2);
      const float2 v = src[f];
      acc.x += v.x * g; acc.y += v.y * g;
    }
    Aw[swz(m)] = acc;
  }
  dif_wav<M1, true>(Aw, sm.tw, l);
#pragma unroll
  for (int i = 0; i < M1 / 64; ++i) {
    const int m = l + 64 * i;
    const float2 v = Aw[swz(m)];
    Aw[swz(m)] = make_float2(sqrtf(v.x * v.x + v.y * v.y) * (1.0f / 2048.0f), 0.0f);
  }
  dit_wav<M1>(Aw, sm.tw, l);
  float2* dst = U1h + (size_t)n * U1H_STRIDE + u1h_off(j1);
#pragma unroll
  for (int i = 0; i < M1 / 64; ++i) {
    const int m = l + 64 * i;
    dst[m] = Aw[swz(m)];
  }
  const float invM = 1.0f / (float)M1;
  const float c0 = Aw[0].x * invM;
  const float2 U1 = Aw[1], U2 = Aw[2], U3 = Aw[3];
  const float k1 = PHI1 * 2.0f * invM, k2 = PHI2 * 2.0f * invM, k3 = PHI3 * 2.0f * invM;
  float part = 0.0f;
#pragma unroll
  for (int i = 0; i < M1 / 64; ++i) {
    const int t = l + 64 * i;
    float sv, cv;
    __sincosf((6.283185307179586f / (float)M1) * (float)t, &sv, &cv);
    float acc = c0 + k1 * (U1.x * cv - U1.y * sv);
    const float c2 = cv * cv - sv * sv, s2 = 2.0f * sv * cv;
    acc += k2 * (U2.x * c2 - U2.y * s2);
    const float c3 = c2 * cv - s2 * sv, s3 = s2 * cv + c2 * sv;
    acc += k3 * (U3.x * c3 - U3.y * s3);
    part += __logf(acc + 1e-6f);
  }
  part = wsum(part);
  if (l == 0) out[((size_t)b * 440 + j1) * 6 + c] = part * invM;
}

// kB_all: 32 blocks/signal: [0,8) 2048 blk; [8,16) 1024 blk; [16,18) 512 wave;
// [18,32) 256 wave.
__global__ __launch_bounds__(NTH, 8) void kB_all(const float2* __restrict__ xh,
                                                 float2* __restrict__ U1h,
                                                 float* __restrict__ out) {
  __shared__ SM sm;
  const int n = (int)blockIdx.x >> 5;
  const int lc = (int)blockIdx.x & 31;
  const int b = n / 6, c = n % 6;
  const float2* src = xh + (size_t)n * 2048;
  if (lc < 8)       kB_blk<2048>(sm, src, U1h, out, n, b, c, lc);
  else if (lc < 16) kB_blk<1024>(sm, src, U1h, out, n, b, c, lc);
  else if (lc < 18) kB_wav<512>(sm, src, U1h, out, n, b, c, 16 + 4 * (lc - 16));
  else              kB_wav<256>(sm, src, U1h, out, n, b, c, 24 + 4 * (lc - 18));
}

// ---------------- Stage C bodies ----------------
template <int M2>
__device__ __forceinline__ void kC_blk(SM& sm, const float2* __restrict__ V,
                                       float* __restrict__ outp, int M1, int F, float xi) {
  init_twM<M2>(sm.tw);
  const float sig = 0.8f * xi;
  const float inv2s2 = 1.0f / (2.0f * sig * sig);
#pragma unroll
  for (int i = 0; i < M2 / NTH; ++i) {
    const int m = (int)threadIdx.x + NTH * i;
    float2 acc = make_float2(0.0f, 0.0f);
    for (int q = 0; q < F; ++q) {
      const int idx = m + q * M2;
      const float fr = (float)(idx < (M1 >> 1) ? idx : idx - M1) * (1.0f / 2048.0f);
      const float d = fr - xi;
      const float g = __expf(-d * d * inv2s2);
      const float2 v = V[idx];
      acc.x += v.x * g; acc.y += v.y * g;
    }
    sm.A[swz(m)] = acc;
  }
  dif_blk<M2, true>(sm.A, sm.tw);  // z2 in P-order
  const float invM1 = 1.0f / (float)M1;
  float cvs[M2 / NTH], svs[M2 / NTH];
  float b0 = 0, b1r = 0, b1i = 0, b2r = 0, b2i = 0, b3r = 0, b3i = 0;
#pragma unroll
  for (int i = 0; i < M2 / NTH; ++i) {
    const int idx = (int)threadIdx.x + NTH * i;
    const float2 v = sm.A[swz(idx)];
    const float u = sqrtf(v.x * v.x + v.y * v.y) * invM1;
    const int t = prevM<M2>(idx);
    float sv, cv;
    __sincosf((6.283185307179586f / (float)M2) * (float)t, &sv, &cv);
    cvs[i] = cv; svs[i] = sv;
    b0 += u;
    b1r += u * cv; b1i -= u * sv;
    const float c2 = cv * cv - sv * sv, s2 = 2.0f * sv * cv;
    b2r += u * c2; b2i -= u * s2;
    const float c3 = c2 * cv - s2 * sv, s3 = s2 * cv + c2 * sv;
    b3r += u * c3; b3i -= u * s3;
  }
  b0 = wsum(b0);
  b1r = wsum(b1r); b1i = wsum(b1i);
  b2r = wsum(b2r); b2i = wsum(b2i);
  b3r = wsum(b3r); b3i = wsum(b3i);
  float* scr = (float*)sm.tw;  // tw dead after dif
  const int lane = (int)threadIdx.x & 63, wid = (int)threadIdx.x >> 6;
  if (lane == 0) {
    scr[wid * 7 + 0] = b0;
    scr[wid * 7 + 1] = b1r; scr[wid * 7 + 2] = b1i;
    scr[wid * 7 + 3] = b2r; scr[wid * 7 + 4] = b2i;
    scr[wid * 7 + 5] = b3r; scr[wid * 7 + 6] = b3i;
  }
  __syncthreads();
  float Bv[7];
#pragma unroll
  for (int bi = 0; bi < 7; ++bi)
    Bv[bi] = scr[bi] + scr[7 + bi] + scr[14 + bi] + scr[21 + bi];
  const float k1 = 2.0f * PHI1, k2 = 2.0f * PHI2, k3 = 2.0f * PHI3;
  const float invM2 = 1.0f / (float)M2;
  float part = 0.0f;
#pragma unroll
  for (int i = 0; i < M2 / NTH; ++i) {
    const float cv = cvs[i], sv = svs[i];
    float acc = Bv[0] + k1 * (Bv[1] * cv - Bv[2] * sv);
    const float c2 = cv * cv - sv * sv, s2 = 2.0f * sv * cv;
    acc += k2 * (Bv[3] * c2 - Bv[4] * s2);
    const float c3 = c2 * cv - s2 * sv, s3 = s2 * cv + c2 * sv;
    acc += k3 * (Bv[5] * c3 - Bv[6] * s3);
    part += __logf(acc * invM2 + 1e-6f);
  }
  part = wsum(part);
  if (lane == 0) scr[28 + wid] = part;
  __syncthreads();
  if (threadIdx.x == 0)
    *outp = (scr[28] + scr[29] + scr[30] + scr[31]) * invM2;
}

template <int M2>
__device__ __forceinline__ void kC_wav(SM& sm, const float2* __restrict__ V,
                                       float* __restrict__ outp, int M1, int F, float xi) {
  init_twM<M2>(sm.tw);
  __syncthreads();  // tw visible; rest barrier-free
  const int l = (int)threadIdx.x & 63, wid = (int)threadIdx.x >> 6;
  float2* Aw = sm.A + wid * M2;
  const float sig = 0.8f * xi;
  const float inv2s2 = 1.0f / (2.0f * sig * sig);
#pragma unroll
  for (int i = 0; i < M2 / 64; ++i) {
    const int m = l + 64 * i;
    float2 acc = make_float2(0.0f, 0.0f);
    for (int q = 0; q < F; ++q) {
      const int idx = m + q * M2;
      const float fr = (float)(idx < (M1 >> 1) ? idx : idx - M1) * (1.0f / 2048.0f);
      const float d = fr - xi;
      const float g = __expf(-d * d * inv2s2);
      const float2 v = V[idx];
      acc.x += v.x * g; acc.y += v.y * g;
    }
    Aw[swz(m)] = acc;
  }
  dif_wav<M2, true>(Aw, sm.tw, l);
  const float invM1 = 1.0f / (float)M1;
  float cvs[M2 / 64], svs[M2 / 64];
  float b0 = 0, b1r = 0, b1i = 0, b2r = 0, b2i = 0, b3r = 0, b3i = 0;
#pragma unroll
  for (int i = 0; i < M2 / 64; ++i) {
    const int idx = l + 64 * i;
    const float2 v = Aw[swz(idx)];
    const float u = sqrtf(v.x * v.x + v.y * v.y) * invM1;
    const int t = prevM<M2>(idx);
    float sv, cv;
    __sincosf((6.283185307179586f / (float)M2) * (float)t, &sv, &cv);
    cvs[i] = cv; svs[i] = sv;
    b0 += u;
    b1r += u * cv; b1i -= u * sv;
    const float c2 = cv * cv - sv * sv, s2 = 2.0f * sv * cv;
    b2r += u * c2; b2i -= u * s2;
    const float c3 = c2 * cv - s2 * sv, s3 = s2 * cv + c2 * sv;
    b3r += u * c3; b3i -= u * s3;
  }
  b0 = wsum(b0);
  b1r = wsum(b1r); b1i = wsum(b1i);
  b2r = wsum(b2r); b2i = wsum(b2i);
  b3r = wsum(b3r); b3i = wsum(b3i);
  const float k1 = 2.0f * PHI1, k2 = 2.0f * PHI2, k3 = 2.0f * PHI3;
  const float invM2 = 1.0f / (float)M2;
  float part = 0.0f;
#pragma unroll
  for (int i = 0; i < M2 / 64; ++i) {
    const float cv = cvs[i], sv = svs[i];
    float acc = b0 + k1 * (b1r * cv - b1i * sv);
    const float c2 = cv * cv - sv * sv, s2 = 2.0f * sv * cv;
    acc += k2 * (b2r * c2 - b2i * s2);
    const float c3 = c2 * cv - s2 * sv, s3 = s2 * cv + c2 * sv;
    acc += k3 * (b3r * c3 - b3i * s3);
    part += __logf(acc * invM2 + 1e-6f);
  }
  part = wsum(part);
  if (l == 0) *outp = part * invM2;
}

// kC_all: 108 blocks/signal (same map as round 3).
__global__ __launch_bounds__(NTH, 8) void kC_all(const float2* __restrict__ U1h,
                                                 float* __restrict__ out) {
  __shared__ SM sm;
  const int n = (int)blockIdx.x / 108;
  const int lc = (int)blockIdx.x % 108;
  const int b = n / 6, c = n % 6;
  const float2* base = U1h + (size_t)n * U1H_STRIDE;
  const int wid = (int)threadIdx.x >> 6;
  if (lc < 8) {
    const int j1 = lc, k = 1;
    const float xi = 0.4f * exp2f(-(float)k);
    const int p = 4 * k * (k - 1) + j1;
    kC_blk<2048>(sm, base + u1h_off(j1), out + ((size_t)b * 440 + 80 + p) * 6 + c,
                 2048, 1, xi);
  } else if (lc < 24) {
    const int j1 = lc - 8, k = 2;
    const int M1 = 2048 >> (j1 >> 3);
    const float xi = 0.4f * exp2f(-(float)k);
    const int p = 4 * k * (k - 1) + j1;
    kC_blk<1024>(sm, base + u1h_off(j1), out + ((size_t)b * 440 + 80 + p) * 6 + c,
                 M1, M1 / 1024, xi);
  } else if (lc < 30) {
    const int g = lc - 24, k = 3;
    const int j1 = 4 * g + wid;
    const int M1 = 2048 >> (j1 >> 3);
    const float xi = 0.4f * exp2f(-(float)k);
    const int p = 4 * k * (k - 1) + j1;
    kC_wav<512>(sm, base + u1h_off(j1), out + ((size_t)b * 440 + 80 + p) * 6 + c,
                M1, M1 / 512, xi);
  } else {
    int bc = lc - 30;  // k=4..9, 2k groups each (8+10+12+14+16+18 = 78)
    int k = 4;
    while (bc >= 2 * k) { bc -= 2 * k; ++k; }
    const int j1 = 4 * bc + wid;
    const int o = j1 >> 3;
    const int M1 = (o < 3) ? (2048 >> o) : 256;
    const float xi = 0.4f * exp2f(-(float)k);
    const int p = 4 * k * (k - 1) + j1;
    kC_wav<256>(sm, base + u1h_off(j1), out + ((size_t)b * 440 + 80 + p) * 6 + c,
                M1, M1 / 256, xi);
  }
}

extern "C" void kernel_launch(void* const* d_in, const int* in_sizes, int n_in,
                              void* d_out, int out_size, void* d_ws, size_t ws_size,
                              hipStream_t stream) {
  (void)in_sizes; (void)n_in; (void)out_size; (void)ws_size;
  const float* x = (const float*)d_in[0];  // [8, 2048, 6] fp32
  float* out = (float*)d_out;              // [8, 440, 6] fp32
  float2* U1h = (float2*)d_ws;                                       // 16.5 MB
  float2* xh = (float2*)((char*)d_ws + (size_t)48 * U1H_STRIDE * sizeof(float2));
  kA<<<dim3(48), dim3(NTH), 0, stream>>>(x, xh);
  kB_all<<<dim3(48 * 32), dim3(NTH), 0, stream>>>(xh, U1h, out);
  kC_all<<<dim3(48 * 108), dim3(NTH), 0, stream>>>(U1h, out);
}